// Round 3
// baseline (133.389 us; speedup 1.0000x reference)
//
#include <hip/hip_runtime.h>
#include <hip/hip_bf16.h>
#include <stdint.h>

// Problem constants: B=4, CIN=COUT=256, H=W=64, 3x3, pad=1, stride=1, dil=1
#define KDIM 2304   // CIN * 9, GEMM K

typedef __bf16 bf16_t;
typedef bf16_t bf16x8 __attribute__((ext_vector_type(8)));
typedef float f32x4 __attribute__((ext_vector_type(4)));
typedef float f32x2 __attribute__((ext_vector_type(2)));

__device__ __forceinline__ float b2f_lo(uint32_t u) {
  union { uint32_t i; float f; } c; c.i = u << 16; return c.f;
}
__device__ __forceinline__ float b2f_hi(uint32_t u) {
  union { uint32_t i; float f; } c; c.i = u & 0xffff0000u; return c.f;
}
__device__ __forceinline__ uint32_t pk_bf16(float a, float b) {
  __hip_bfloat162 h = __float22bfloat162_rn(make_float2(a, b));
  union { __hip_bfloat162 h; uint32_t u; } c; c.h = h; return c.u;
}

// ---------------- merged prep kernel
// blocks [0,2048): x [4][256][64][64] f32 -> xt [4][64][64][256] bf16 (NHWC)
// blocks [2048,2084): weight -> wt2 fragment-linear bf16:
//   wt2[i(36)][slot(2048)][8] where slot = strip*... laid so that consumer wave
//   'strip' (16 strips of 16 rows) reads: wt2 + i*16384 + strip*1024 + kh*512 + lane*8
//   element = w[row=strip*16+(lane&15)][cin=(i&3)*64+kh*32+(lane>>4)*8+e][tap=i>>2]
__global__ __launch_bounds__(256) void k_prep(const float* __restrict__ x,
                                              uint16_t* __restrict__ xt,
                                              const float* __restrict__ w,
                                              uint16_t* __restrict__ wt2) {
  int tid = threadIdx.x;
  if (blockIdx.x < 2048) {
    __shared__ float tile[32][65];
    int b = blockIdx.x >> 9;
    int cgrp = (blockIdx.x >> 6) & 7;
    int sgrp = blockIdx.x & 63;
    int c0 = cgrp << 5, s0 = sgrp << 6;
#pragma unroll
    for (int it = 0; it < 2; ++it) {
      int f = tid + it * 256;
      int rr = f >> 4, col = (f & 15) << 2;
      float4 v = *(const float4*)&x[((size_t)(b * 256 + c0 + rr)) * 4096 + s0 + col];
      tile[rr][col + 0] = v.x;
      tile[rr][col + 1] = v.y;
      tile[rr][col + 2] = v.z;
      tile[rr][col + 3] = v.w;
    }
    __syncthreads();
    int sp = tid >> 2, cg = tid & 3;
    uint4 o;
    o.x = pk_bf16(tile[cg * 8 + 0][sp], tile[cg * 8 + 1][sp]);
    o.y = pk_bf16(tile[cg * 8 + 2][sp], tile[cg * 8 + 3][sp]);
    o.z = pk_bf16(tile[cg * 8 + 4][sp], tile[cg * 8 + 5][sp]);
    o.w = pk_bf16(tile[cg * 8 + 6][sp], tile[cg * 8 + 7][sp]);
    *(uint4*)&xt[((size_t)b * 4096 + s0 + sp) * 256 + c0 + cg * 8] = o;
  } else {
    int i = blockIdx.x - 2048;          // 0..35
    int tap = i >> 2, w64 = i & 3;
    uint16_t* dst = wt2 + (size_t)i * 16384;
#pragma unroll
    for (int s = 0; s < 8; ++s) {
      int slot = tid + s * 256;         // 0..2047 = strip*128 + kh*64 + lane
      int lane = slot & 63;
      int kh = (slot >> 6) & 1, strip = slot >> 7;
      int row = strip * 16 + (lane & 15);
      int cin0 = w64 * 64 + kh * 32 + ((lane >> 4) << 3);
      const float* src = w + (size_t)row * KDIM + (size_t)cin0 * 9 + tap;
      uint4 o;
      o.x = pk_bf16(src[0 * 9], src[1 * 9]);
      o.y = pk_bf16(src[2 * 9], src[3 * 9]);
      o.z = pk_bf16(src[4 * 9], src[5 * 9]);
      o.w = pk_bf16(src[6 * 9], src[7 * 9]);
      *(uint4*)(dst + (size_t)slot * 8) = o;
    }
  }
}

// per-thread bilinear corner setup for one tap (full 64-position row, wo = p)
__device__ __forceinline__ void mk_corners(int tap, int p, int ho,
                                           const float* s_off, const float* s_msk,
                                           float cw[4], int cpo[4]) {
  int kh = tap / 3, kw = tap - kh * 3;
  float dy = s_off[(2 * tap) * 64 + p];
  float dx = s_off[(2 * tap + 1) * 64 + p];
  float mm = s_msk[tap * 64 + p];
  float sy = (float)(ho - 1 + kh) + dy;
  float sx = (float)(p - 1 + kw) + dx;
  float fy = floorf(sy), fx = floorf(sx);
  int y0 = (int)fy, x0 = (int)fx;
  float wy = sy - fy, wx = sx - fx;
#pragma unroll
  for (int cy = 0; cy < 2; ++cy) {
#pragma unroll
    for (int cx = 0; cx < 2; ++cx) {
      int y = y0 + cy, xx = x0 + cx;
      float wgt = (cy ? wy : 1.f - wy) * (cx ? wx : 1.f - wx) * mm;
      bool v = ((unsigned)y < 64u) && ((unsigned)xx < 64u);
      wgt = v ? wgt : 0.f;
      int yc = min(max(y, 0), 63), xc = min(max(xx, 0), 63);
      cw[cy * 2 + cx] = wgt;
      cpo[cy * 2 + cx] = ((yc << 6) + xc) * 256;
    }
  }
}

// ---------------- FUSED deform-im2col + GEMM, register-A, 16 waves/block
// Block: 1024 thr = 16 waves (4/SIMD). BM=256, BN=64 (one full (b,ho) row ->
// each block writes whole 256B out rows: no cross-block line sharing), BK=64.
// Grid 256 = 1 block/CU; __launch_bounds__(1024,4) caps VGPR at 128 (no spill,
// ~90 used). A (weight) global->VGPR from fragment-linear wt2 (L2-resident,
// coalesced 1KB/wave), register double-buffered: no As LDS, no global_load_lds,
// so __syncthreads only fences the small swizzled Bs. Bs rows are 128B with
// XOR 16B-chunk swizzle (write+read) -> conflict-free ds ops (T2).
__global__ __launch_bounds__(1024, 4) void k_fused(const uint16_t* __restrict__ xt,
                                                   const uint16_t* __restrict__ wt2,
                                                   const float* __restrict__ off,
                                                   const float* __restrict__ msk,
                                                   const float* __restrict__ bias,
                                                   float* __restrict__ out) {
  __shared__ __align__(16) uint16_t Bs[2][64][64];  // 16 KB [buf][pos][k], swizzled
  __shared__ float s_off[18 * 64];
  __shared__ float s_msk[9 * 64];

  int tid = threadIdx.x;
  // XCD-aware swizzle (256 = 8*32, bijective): each XCD gets 32 consecutive
  // (b,ho) -> at most one b per XCD, xt slice fits its L2.
  int swz = ((int)blockIdx.x & 7) * 32 + ((int)blockIdx.x >> 3);
  int b = swz >> 6, ho = swz & 63;

  const float* offb = off + (size_t)b * 18 * 4096 + ho * 64;
  for (int i = tid; i < 18 * 64; i += 1024)
    s_off[i] = offb[(size_t)(i >> 6) * 4096 + (i & 63)];
  const float* mskb = msk + (size_t)b * 9 * 4096 + ho * 64;
  for (int i = tid; i < 9 * 64; i += 1024)
    s_msk[i] = mskb[(size_t)(i >> 6) * 4096 + (i & 63)];

  int lane = tid & 63, strip = tid >> 6;    // 16 waves = 16 M-strips of 16 rows
  int q = lane >> 4, r = lane & 15;
  // B gather mapping: position p (0..63), 4-channel chunk cg (0..15)
  int p = tid >> 4, cg = tid & 15;
  const uint16_t* xtb = xt + (size_t)b * 4096 * 256 + cg * 4;
  int bcol = (((cg >> 1) ^ (p & 7)) << 3) + ((cg & 1) << 2);  // swizzled u16 col

  f32x4 acc[4];
#pragma unroll
  for (int ni = 0; ni < 4; ++ni) acc[ni] = f32x4{0.f, 0.f, 0.f, 0.f};

  __syncthreads();  // off/msk staged

  float cw[4];
  int cpo[4];
  uint2 dnv[4];
  bf16x8 AFA[2], AFB[2];

  int c0 = (q ^ (r & 7)) << 3;   // swizzled u16 col for kh=0 fragment
  int c1 = c0 ^ 32;              // kh=1: chunk ^ 4 -> col ^ 32

  // ---- prologue: tile 0 -> Bs[0]; A fragments for iter 0 -> AFA
  mk_corners(0, p, ho, s_off, s_msk, cw, cpo);
#pragma unroll
  for (int c = 0; c < 4; ++c) dnv[c] = *(const uint2*)(xtb + cpo[c]);
  {
    const uint16_t* wp = wt2 + strip * 1024 + lane * 8;
    AFA[0] = *(const bf16x8*)(wp);
    AFA[1] = *(const bf16x8*)(wp + 512);
  }
  {
    f32x2 a0 = {0.f, 0.f}, a1 = {0.f, 0.f};
#pragma unroll
    for (int c = 0; c < 4; ++c) {
      f32x2 wc = {cw[c], cw[c]};
      a0 += wc * f32x2{b2f_lo(dnv[c].x), b2f_hi(dnv[c].x)};
      a1 += wc * f32x2{b2f_lo(dnv[c].y), b2f_hi(dnv[c].y)};
    }
    uint2 o;
    o.x = pk_bf16(a0.x, a0.y);
    o.y = pk_bf16(a1.x, a1.y);
    *(uint2*)&Bs[0][p][bcol] = o;
  }
  __syncthreads();

#define BODY(IEXPR, AFC, AFN)                                                   \
  {                                                                             \
    const int i_ = (IEXPR);                                                     \
    if (i_ < 35) {                                                              \
      int nx = i_ + 1;                                                          \
      if ((nx & 3) == 0) mk_corners(nx >> 2, p, ho, s_off, s_msk, cw, cpo);     \
      int chw = (nx & 3) << 6;                                                  \
      _Pragma("unroll")                                                         \
      for (int c = 0; c < 4; ++c) dnv[c] = *(const uint2*)(xtb + cpo[c] + chw); \
      const uint16_t* wp = wt2 + (size_t)nx * 16384 + strip * 1024 + lane * 8;  \
      AFN[0] = *(const bf16x8*)(wp);                                            \
      AFN[1] = *(const bf16x8*)(wp + 512);                                      \
    }                                                                           \
    {                                                                           \
      const uint16_t* bsrow = &Bs[(IEXPR) & 1][0][0];                           \
      _Pragma("unroll")                                                         \
      for (int ni = 0; ni < 4; ++ni) {                                          \
        bf16x8 b0 = *(const bf16x8*)(bsrow + (ni * 16 + r) * 64 + c0);          \
        bf16x8 b1 = *(const bf16x8*)(bsrow + (ni * 16 + r) * 64 + c1);          \
        acc[ni] = __builtin_amdgcn_mfma_f32_16x16x32_bf16(AFC[0], b0, acc[ni], 0, 0, 0); \
        acc[ni] = __builtin_amdgcn_mfma_f32_16x16x32_bf16(AFC[1], b1, acc[ni], 0, 0, 0); \
      }                                                                         \
    }                                                                           \
    if (i_ < 35) {                                                              \
      f32x2 a0 = {0.f, 0.f}, a1 = {0.f, 0.f};                                   \
      _Pragma("unroll")                                                         \
      for (int c = 0; c < 4; ++c) {                                             \
        f32x2 wc = {cw[c], cw[c]};                                              \
        a0 += wc * f32x2{b2f_lo(dnv[c].x), b2f_hi(dnv[c].x)};                   \
        a1 += wc * f32x2{b2f_lo(dnv[c].y), b2f_hi(dnv[c].y)};                   \
      }                                                                         \
      uint2 o;                                                                  \
      o.x = pk_bf16(a0.x, a0.y);                                                \
      o.y = pk_bf16(a1.x, a1.y);                                                \
      *(uint2*)&Bs[1 - ((IEXPR) & 1)][p][bcol] = o;                             \
    }                                                                           \
    __syncthreads();                                                            \
  }

#pragma unroll 1
  for (int ii = 0; ii < 18; ++ii) {
    BODY(2 * ii, AFA, AFB);
    BODY(2 * ii + 1, AFB, AFA);
  }
#undef BODY

  // epilogue: C/D layout col(n) = lane&15 = r, row(m) = q*4 + j
#pragma unroll
  for (int j = 0; j < 4; ++j) {
    int m = strip * 16 + q * 4 + j;
    float bv = bias[m];
#pragma unroll
    for (int ni = 0; ni < 4; ++ni) {
      out[((size_t)(b * 256 + m)) * 4096 + ho * 64 + ni * 16 + r] = acc[ni][j] + bv;
    }
  }
}

extern "C" void kernel_launch(void* const* d_in, const int* in_sizes, int n_in,
                              void* d_out, int out_size, void* d_ws, size_t ws_size,
                              hipStream_t stream) {
  (void)in_sizes; (void)n_in; (void)out_size; (void)ws_size;
  const float* x      = (const float*)d_in[0];  // [4][256][64][64]
  const float* offset = (const float*)d_in[1];  // [4][18][64][64]
  const float* mask   = (const float*)d_in[2];  // [4][9][64][64]
  const float* weight = (const float*)d_in[3];  // [256][256][3][3]
  const float* bias   = (const float*)d_in[4];  // [256]
  float* out = (float*)d_out;                   // [4][256][64][64]

  uint8_t* ws = (uint8_t*)d_ws;
  uint16_t* xt  = (uint16_t*)ws;                // 8,388,608 B : NHWC bf16
  uint16_t* wt2 = (uint16_t*)(ws + 8388608);    // 1,179,648 B : fragment-linear

  k_prep<<<dim3(2084), 256, 0, stream>>>(x, xt, weight, wt2);
  k_fused<<<dim3(256), 1024, 0, stream>>>(xt, wt2, offset, mask, bias, out);
}